// Round 8
// baseline (264.191 us; speedup 1.0000x reference)
//
#include <hip/hip_runtime.h>
#include <cstdint>
#include <cstddef>

#define BB 4
#define CC 19
#define HH 512
#define WW 1024
#define HW (HH*WW)          // 524288
#define HW4 (HW/4)          // 131072
#define KTOP 256
#define EPSF 1e-6f
#define NB1 4096            // coarse bins: key >> 20
#define NB2 8192            // refine bins: (key >> 7) & 0x1FFF
#define LSTRIDE 1032        // padded LDS row stride, data at col 4..1027
#define LOGC 2.9444389791664403f   // ln(19)

#define NSEG 64             // segments per image (8 rows each)
#define RPB 8               // rows per block
#define NBLK (BB*NSEG)      // 256 blocks, 1/CU, co-resident (capacity-proven)
#define TPB 1024            // 16 waves/CU

__device__ __forceinline__ unsigned int sortable(float x) {
    unsigned int u = __float_as_uint(x);
    return (u & 0x80000000u) ? ~u : (u | 0x80000000u);
}
__device__ __forceinline__ float unsortable(unsigned int K) {
    unsigned int u = (K & 0x80000000u) ? (K & 0x7FFFFFFFu) : ~K;
    return __uint_as_float(u);
}
// relaxed agent-scope atomics: cross-XCD coherent, NO L2 flush (Guideline 16)
__device__ __forceinline__ unsigned int agld(const unsigned int* p) {
    return __hip_atomic_load(p, __ATOMIC_RELAXED, __HIP_MEMORY_SCOPE_AGENT);
}

// ---- LDS phase union ----
struct P1Mem {
    float ent_s[(RPB + 2) * LSTRIDE];          // 41280 B  (rows r0-1 .. r0+8)
    unsigned char pred_s[(RPB + 2) * LSTRIDE]; // 10320 B
    unsigned int lh1[NB1];                     // 16384 B
};
struct P2Mem {
    unsigned int lh2[NB2];                     // 32768 B
    float ls2[NB2];                            // 32768 B
};
union UMem { P1Mem p1; P2Mem p2; };            // 67984 B

// ---- top-down bin selection over 1024*CPT bins, 1024 threads, agld reads ----
template<int CPT>
__device__ __forceinline__ void sel_topdown(const unsigned int* __restrict__ hb,
                                            int rem, unsigned int* cs, unsigned int* bs,
                                            int* s3, int* bin_out, int* rem_out) {
    int t = threadIdx.x;
    unsigned int s = 0;
#pragma unroll
    for (int i = 0; i < CPT; ++i) s += agld(&hb[t * CPT + i]);
    cs[t] = s;
    __syncthreads();
    for (int d = 1; d < 1024; d <<= 1) {       // suffix scan over 1024 chunks
        unsigned int v = (t + d < 1024) ? cs[t + d] : 0;
        __syncthreads();
        cs[t] += v;
        __syncthreads();
    }
    unsigned int St = cs[t];
    unsigned int St1 = (t < 1023) ? cs[t + 1] : 0;
    if ((int)St >= rem && (t == 1023 || (int)St1 < rem)) {
        s3[0] = t; s3[2] = rem - (int)St1;
    }
    __syncthreads();
    int chunk = s3[0], rem2 = s3[2];
    if (t < CPT) bs[t] = agld(&hb[chunk * CPT + t]);
    __syncthreads();
    if (t == 0) {                              // tiny within-chunk suffix walk
        int acc = 0, bin = chunk * CPT, rr = rem2;
        for (int j = CPT - 1; j >= 0; --j) {
            acc += (int)bs[j];
            if (acc >= rem2) { bin = chunk * CPT + j; rr = rem2 - (acc - (int)bs[j]); break; }
        }
        s3[1] = bin; s3[2] = rr;
    }
    __syncthreads();
    *bin_out = s3[1];
    *rem_out = s3[2];
}

// ---- init: zero hist1|hist2|hsum|done1|done2 + out ----
__global__ __launch_bounds__(1024) void k_init(unsigned int* __restrict__ histb,
                                               float* __restrict__ out) {
    int i = blockIdx.x * 1024 + threadIdx.x;
    if (i < 81928) histb[i] = 0u;     // 81920 hist words + 4 done1 + 4 done2
    if (i < BB) out[i] = 0.f;
}

// ==================== single fused kernel (no cross-block data handoff) ====================
__global__ __launch_bounds__(1024, 4) void k_fused(const float* __restrict__ logit,
                                                   unsigned int* __restrict__ histb,
                                                   float* __restrict__ out) {
    __shared__ __align__(16) UMem U;
    __shared__ float lgt[48];
    __shared__ unsigned int cs[1024];
    __shared__ unsigned int bs[8];
    __shared__ int s3[3];
    __shared__ float red[16];
    __shared__ int islast;

    int tid = threadIdx.x;
    int tx = tid & 255;                 // quad column
    int ty = tid >> 8;                  // 0..3
    int b = blockIdx.x >> 6;            // image
    int seg = blockIdx.x & (NSEG - 1);  // 8-row segment
    int r0 = seg * RPB;

    unsigned int* hist1 = histb;                      // 4*4096 words
    unsigned int* hist2 = histb + 16384;              // 4*8192 words
    float*        hsum  = (float*)(histb + 49152);    // 4*8192 words
    unsigned int* done1 = histb + 81920;              // 4
    unsigned int* done2 = histb + 81924;              // 4

    if (tid < 48) {
        int nvi = tid >> 4, cnt = tid & 15;
        float nv = (nvi == 0) ? 4.f : (nvi == 1) ? 6.f : 9.f;
        lgt[tid] = __logf((float)cnt / nv + EPSF);
    }
    for (int i = tid; i < (RPB + 2) * LSTRIDE; i += TPB) { U.p1.ent_s[i] = 0.f; U.p1.pred_s[i] = 255; }
    for (int i = tid; i < NB1; i += TPB) U.p1.lh1[i] = 0;
    __syncthreads();

    // ---- P0: entropy + argmax for rows r0-1 .. r0+8 (redundant halo compute) ----
    // All 19 class loads batched BEFORE any consumption; sched_barrier(0) forbids
    // the scheduler from sinking loads into the consumer loop (R6: without it the
    // compiler re-interleaved for VGPR=64 and killed memory-level parallelism).
    // Compiler inserts progressive s_waitcnt vmcnt(18..0) per consumption.
    {
        const float4* bb4 = (const float4*)logit + (size_t)b * CC * HW4;
        for (int t = tid; t < (RPB + 2) * 256; t += TPB) {   // 2560 quad-tasks
            int lr = t >> 8;                  // LDS row 0..9
            int cq = t & 255;                 // quad column
            int g = r0 - 1 + lr;              // global row
            if (g < 0 || g >= HH) continue;
            const float4* basep = bb4 + (size_t)g * 256 + cq;
            float4 pr[19];                    // fully unrolled: compile-time indices
#pragma unroll
            for (int c = 0; c < CC; ++c) pr[c] = basep[(size_t)c * HW4];
            __builtin_amdgcn_sched_barrier(0);    // loads stay batched above this line
            float e0 = 0.f, e1 = 0.f, e2 = 0.f, e3 = 0.f;
            float m0 = -1.f, m1 = -1.f, m2 = -1.f, m3 = -1.f;
            int a0 = 0, a1 = 0, a2 = 0, a3 = 0;
#pragma unroll
            for (int c = 0; c < CC; ++c) {
                float4 p = pr[c];
                e0 -= p.x * __logf(p.x + EPSF); if (p.x > m0) { m0 = p.x; a0 = c; }
                e1 -= p.y * __logf(p.y + EPSF); if (p.y > m1) { m1 = p.y; a1 = c; }
                e2 -= p.z * __logf(p.z + EPSF); if (p.z > m2) { m2 = p.z; a2 = c; }
                e3 -= p.w * __logf(p.w + EPSF); if (p.w > m3) { m3 = p.w; a3 = c; }
            }
            *(float4*)&U.p1.ent_s[lr * LSTRIDE + 4 + cq * 4] = make_float4(e0, e1, e2, e3);
            unsigned int pw = (unsigned int)a0 | ((unsigned int)a1 << 8) |
                              ((unsigned int)a2 << 16) | ((unsigned int)a3 << 24);
            *(unsigned int*)&U.p1.pred_s[lr * LSTRIDE + 4 + cq * 4] = pw;
        }
    }
    __syncthreads();

    // ---- P1: score 8 px/thread (rows r0+ty, r0+ty+4; cols 4tx..4tx+3) ----
    float sv[8];
#pragma unroll
    for (int it = 0; it < 2; ++it) {
        int k = ty + it * 4;                  // local pixel row; window = LDS rows k..k+2
        float r3[3][6];
        int p3[3][6];
#pragma unroll
        for (int rr = 0; rr < 3; ++rr) {
            const float* rowp = &U.p1.ent_s[(k + rr) * LSTRIDE + 4];
            const unsigned char* prow = &U.p1.pred_s[(k + rr) * LSTRIDE + 4];
            float4 m = *(const float4*)&rowp[tx * 4];
            r3[rr][0] = rowp[tx * 4 - 1];     // col pad (0) at w==0 edge
            r3[rr][1] = m.x; r3[rr][2] = m.y; r3[rr][3] = m.z; r3[rr][4] = m.w;
            r3[rr][5] = rowp[tx * 4 + 4];
            uchar4 pm = *(const uchar4*)&prow[tx * 4];
            p3[rr][0] = prow[tx * 4 - 1];     // 255 pad
            p3[rr][1] = pm.x; p3[rr][2] = pm.y; p3[rr][3] = pm.z; p3[rr][4] = pm.w;
            p3[rr][5] = prow[tx * 4 + 4];
        }
        int h = r0 + k;
        int hn = (h > 0) + (h < HH - 1) + 1;
#pragma unroll
        for (int q = 0; q < 4; ++q) {
            int w = tx * 4 + q;
            float es = 0.f;
#pragma unroll
            for (int i = 0; i < 9; ++i) es += r3[i / 3][q + i % 3];   // same add order
            int cls[9];
#pragma unroll
            for (int i = 0; i < 9; ++i) cls[i] = p3[i / 3][q + i % 3];
            int nv = hn * ((w > 0) + (w < WW - 1) + 1);
            float inv = 1.f / (float)nv;
            int nvi = (nv == 9) ? 2 : ((nv == 6) ? 1 : 0);
            const float* lg = &lgt[nvi * 16];
            float lsum = 0.f;
#pragma unroll
            for (int i = 0; i < 9; ++i) {
                int cnt = 0;
#pragma unroll
                for (int j = 0; j < 9; ++j) cnt += (cls[j] == cls[i]) ? 1 : 0;
                float lv = lg[cnt];
                lsum += (cls[i] != 255) ? lv : 0.f;
            }
            float imp = -inv * lsum;
            float v = (es * (1.f / (9.f * LOGC))) * (imp * (1.f / LOGC));
            sv[it * 4 + q] = v;
            atomicAdd(&U.p1.lh1[sortable(v) >> 20], 1u);   // plain LDS atomic (R0-proven)
        }
    }
    __syncthreads();
    {
        unsigned int* hb = hist1 + (size_t)b * NB1;
        for (int i = tid; i < NB1; i += TPB) {
            unsigned int c = U.p1.lh1[i];
            if (c) atomicAdd(&hb[i], c);             // device-scope by default
        }
    }
    // ---- per-image barrier: syncthreads drains the block's atomics first ----
    __syncthreads();
    if (tid == 0) {
        __hip_atomic_fetch_add(&done1[b], 1u, __ATOMIC_RELAXED, __HIP_MEMORY_SCOPE_AGENT);
        while (agld(&done1[b]) < (unsigned int)NSEG) __builtin_amdgcn_s_sleep(8);
    }
    __syncthreads();

    // ---- P2: coarse select + refine hist + strict-above sum ----
    int bin1, rem1;
    sel_topdown<4>(hist1 + (size_t)b * NB1, KTOP, cs, bs, s3, &bin1, &rem1);
    unsigned int t1 = (unsigned int)bin1;
    for (int i = tid; i < NB2; i += TPB) { U.p2.lh2[i] = 0; U.p2.ls2[i] = 0.f; }
    __syncthreads();
    float sa = 0.f;                               // sum strictly above the T1 coarse bin
#pragma unroll
    for (int j = 0; j < 8; ++j) {
        float vv = sv[j];
        unsigned int k = sortable(vv);
        unsigned int cb = k >> 20;
        if (cb > t1) sa += vv;
        else if (cb == t1) {
            int sub = (k >> 7) & 0x1FFF;
            atomicAdd(&U.p2.lh2[sub], 1u);
            atomicAdd(&U.p2.ls2[sub], vv);
        }
    }
    __syncthreads();
    {
        unsigned int* hb = hist2 + (size_t)b * NB2;
        float* sb = hsum + (size_t)b * NB2;
        for (int i = tid; i < NB2; i += TPB) {
            unsigned int c = U.p2.lh2[i];
            if (c) { atomicAdd(&hb[i], c); atomicAdd(&sb[i], U.p2.ls2[i]); }
        }
    }
#pragma unroll
    for (int d = 32; d; d >>= 1) sa += __shfl_down(sa, d);
    if ((tid & 63) == 0) red[tid >> 6] = sa;
    __syncthreads();
    if (tid == 0) {
        float tt = 0.f;
#pragma unroll
        for (int i = 0; i < 16; ++i) tt += red[i];
        if (tt != 0.f) atomicAdd(&out[b], tt);
    }
    // ---- done-counter handoff: last block per image finishes ----
    __syncthreads();
    if (tid == 0) {
        unsigned int prev = __hip_atomic_fetch_add(&done2[b], 1u, __ATOMIC_RELAXED,
                                                   __HIP_MEMORY_SCOPE_AGENT);
        islast = (prev == (unsigned int)(NSEG - 1)) ? 1 : 0;
    }
    __syncthreads();
    if (islast) {                                  // block-uniform branch
        int bin, rem;
        sel_topdown<8>(hist2 + (size_t)b * NB2, rem1, cs, bs, s3, &bin, &rem);
        const unsigned int* sb = (const unsigned int*)(hsum + (size_t)b * NB2);
        float* rsf = (float*)cs;                   // reuse scan scratch
        float s = 0.f;
        for (int i = tid; i < NB2; i += TPB)
            if (i > bin) s += __uint_as_float(agld(&sb[i]));
        rsf[tid] = s;
        __syncthreads();
        for (int d = 512; d; d >>= 1) {
            if (tid < d) rsf[tid] += rsf[tid + d];
            __syncthreads();
        }
        if (tid == 0) {
            unsigned int K = (t1 << 20) | ((unsigned int)bin << 7);
            atomicAdd(&out[b], rsf[0] + unsortable(K) * (float)rem);  // ties at bin edge
        }
    }
}

extern "C" void kernel_launch(void* const* d_in, const int* in_sizes, int n_in,
                              void* d_out, int out_size, void* d_ws, size_t ws_size,
                              hipStream_t stream) {
    const float* logit = (const float*)d_in[0];
    float* out = (float*)d_out;
    unsigned int* histb = (unsigned int*)d_ws;     // hist1|hist2|hsum|done1|done2 = 81928 words

    k_init<<<81, 1024, 0, stream>>>(histb, out);
    k_fused<<<NBLK, TPB, 0, stream>>>(logit, histb, out);
}